// Round 1
// baseline (999.674 us; speedup 1.0000x reference)
//
#include <hip/hip_runtime.h>
#include <hip/hip_bf16.h>

#define TTOK  1024
#define HDIM  2048
#define IDIM  1408
#define NEXP  16
#define SIDIM 2816
#define RSCALE 2.5f

typedef __bf16 bf16_t;
typedef bf16_t bf16x8 __attribute__((ext_vector_type(8)));
typedef float  f32x4  __attribute__((ext_vector_type(4)));

// ---------------- workspace layout (bytes) ----------------
static const size_t OFF_XBF   = 0;                        // 1024*2048*2 = 4194304
static const size_t OFF_HBUF  = 4194304;                  // 6144*1408*2 = 17301504
static const size_t OFF_SHBUF = OFF_HBUF + 17301504;      // 1024*2816*2 = 5767168
static const size_t OFF_TOPKI = OFF_SHBUF + 5767168;      // 1024*4 int
static const size_t OFF_TOPKW = OFF_TOPKI + 16384;        // 1024*4 float
static const size_t OFF_TOKL  = OFF_TOPKW + 16384;        // 6144 int
static const size_t OFF_WGTL  = OFF_TOKL + 24576;         // 6144 float
static const size_t OFF_CNT   = OFF_WGTL + 24576;         // 16 int
static const size_t OFF_POFF  = OFF_CNT + 256;            // 16 int
// total ~27.4 MB

union Pack4 { bf16_t b[4]; unsigned long long u64; };

__device__ __forceinline__ f32x4 mfma16(bf16x8 a, bf16x8 b, f32x4 c) {
    return __builtin_amdgcn_mfma_f32_16x16x32_bf16(a, b, c, 0, 0, 0);
}
// LDS tile: [128 rows][64 bf16], 16B-slot XOR swizzle -> conflict-free ds_read_b128
__device__ __forceinline__ bf16x8 frag_read(const bf16_t* lds, int row, int slot) {
    int sw = slot ^ (row & 7);
    return *(const bf16x8*)(lds + row * 64 + sw * 8);
}

// ---------------- fp32 -> bf16 convert ----------------
__global__ __launch_bounds__(256) void k_convert(const float* __restrict__ x,
                                                 bf16_t* __restrict__ xb, int n) {
    int i = (blockIdx.x * 256 + threadIdx.x) * 4;
    if (i < n) {
        float4 v = *(const float4*)(x + i);
        Pack4 p;
        p.b[0] = (bf16_t)v.x; p.b[1] = (bf16_t)v.y;
        p.b[2] = (bf16_t)v.z; p.b[3] = (bf16_t)v.w;
        *(unsigned long long*)(xb + i) = p.u64;
    }
}

// ---------------- gate: logits, sigmoid, group top-2, top-4, normalize ----------------
__global__ __launch_bounds__(256) void k_gate(const float* __restrict__ x,
                                              const float* __restrict__ gw,
                                              const float* __restrict__ gb,
                                              int* __restrict__ topki,
                                              float* __restrict__ topkw,
                                              int* __restrict__ counts) {
    int t = blockIdx.x;
    int tid = threadIdx.x;
    int e = tid >> 4, li = tid & 15;
    const float* xr = x + (size_t)t * HDIM;
    const float* wr = gw + (size_t)e * HDIM;
    float s = 0.f;
#pragma unroll
    for (int j = 0; j < 32; ++j) {
        int off = (j * 16 + li) * 4;
        float4 a = *(const float4*)(xr + off);
        float4 b = *(const float4*)(wr + off);
        s += a.x * b.x + a.y * b.y + a.z * b.z + a.w * b.w;
    }
    __shared__ float red[16][16];
    __shared__ float scores[16];
    red[e][li] = s;
    __syncthreads();
    if (tid < 16) {
        float acc = 0.f;
#pragma unroll
        for (int j = 0; j < 16; ++j) acc += red[tid][j];
        scores[tid] = 1.f / (1.f + expf(-acc)) + gb[tid];
    }
    __syncthreads();
    if (tid == 0) {
        float gsc[4];
#pragma unroll
        for (int g = 0; g < 4; ++g) {
            float m = scores[g * 4];
            for (int j = 1; j < 4; ++j) m = fmaxf(m, scores[g * 4 + j]);
            gsc[g] = m;
        }
        bool gsel[4] = {false, false, false, false};
        for (int k = 0; k < 2; ++k) {             // top-2 groups, ties -> lower idx
            int best = 0; float bv = -1e30f;
            for (int g = 0; g < 4; ++g)
                if (!gsel[g] && gsc[g] > bv) { bv = gsc[g]; best = g; }
            gsel[best] = true;
        }
        float msc[16];
        for (int i = 0; i < 16; ++i) msc[i] = gsel[i >> 2] ? scores[i] : -1.f;
        int bidx[4]; float bw[4]; float wsum = 0.f;
        for (int k = 0; k < 4; ++k) {             // top-4 experts, ties -> lower idx
            int best = 0; float bv = -2e30f;
            for (int i = 0; i < 16; ++i)
                if (msc[i] > bv) { bv = msc[i]; best = i; }
            msc[best] = -3e30f;
            bidx[k] = best; bw[k] = bv; wsum += bv;
        }
        float inv = 1.f / (wsum + 1e-6f);
        for (int k = 0; k < 4; ++k) {
            topki[t * 4 + k] = bidx[k];
            topkw[t * 4 + k] = bw[k] * inv * RSCALE;
            atomicAdd(&counts[bidx[k]], 1);
        }
    }
}

// ---------------- exclusive scan of padded counts ----------------
__global__ void k_scan(const int* __restrict__ counts, int* __restrict__ poff) {
    if (threadIdx.x == 0 && blockIdx.x == 0) {
        int acc = 0;
        for (int e = 0; e < NEXP; ++e) {
            poff[e] = acc;
            acc += (counts[e] + 127) & ~127;
        }
    }
}

// ---------------- per-expert token compaction (order-preserving) ----------------
__global__ __launch_bounds__(64) void k_compact(const int* __restrict__ topki,
                                                const float* __restrict__ topkw,
                                                const int* __restrict__ counts,
                                                const int* __restrict__ poff,
                                                int* __restrict__ tokl,
                                                float* __restrict__ wgtl) {
    int e = blockIdx.x;
    int lane = threadIdx.x;
    int base = poff[e];
    int cur = 0;
    for (int t0 = 0; t0 < TTOK; t0 += 64) {
        int t = t0 + lane;
        int4   idx = *(const int4*)(topki + t * 4);
        float4 wv  = *(const float4*)(topkw + t * 4);
        bool has = false; float w = 0.f;
        if      (idx.x == e) { has = true; w = wv.x; }
        else if (idx.y == e) { has = true; w = wv.y; }
        else if (idx.z == e) { has = true; w = wv.z; }
        else if (idx.w == e) { has = true; w = wv.w; }
        unsigned long long b = __ballot(has);
        int pos = cur + __popcll(b & ((1ull << lane) - 1ull));
        if (has) { tokl[base + pos] = t; wgtl[base + pos] = w; }
        cur += __popcll(b);
    }
    int padded = (counts[e] + 127) & ~127;
    for (int i = cur + lane; i < padded; i += 64) {
        tokl[base + i] = -1; wgtl[base + i] = 0.f;
    }
}

// ---------------- routed MLP part 1: h = silu(X Wg^T) * (X Wu^T) ----------------
__global__ __launch_bounds__(256, 2) void k_mlp1_routed(
        const bf16_t* __restrict__ xb, const float* __restrict__ wg,
        const float* __restrict__ wu, const int* __restrict__ counts,
        const int* __restrict__ poff, const int* __restrict__ tokl,
        bf16_t* __restrict__ hbuf) {
    int bid = blockIdx.x;
    int e = bid / 88, rem = bid % 88;
    int mt = rem / 11, nt = rem % 11;
    int cnt = counts[e];
    if (mt * 128 >= cnt) return;
    int rowbase = poff[e] + mt * 128;
    const float* wgp = wg + (size_t)e * IDIM * HDIM + (size_t)(nt * 128) * HDIM;
    const float* wup = wu + (size_t)e * IDIM * HDIM + (size_t)(nt * 128) * HDIM;

    __shared__ bf16_t aL[128 * 64];
    __shared__ bf16_t gL[128 * 64];
    __shared__ bf16_t uL[128 * 64];

    int tid = threadIdx.x;
    int lane = tid & 63;
    int wid = tid >> 6;
    int wm = wid >> 1, wn = wid & 1;

    f32x4 accg[4][4], accu[4][4];
#pragma unroll
    for (int m = 0; m < 4; ++m)
#pragma unroll
        for (int n = 0; n < 4; ++n) {
            accg[m][n] = (f32x4){0.f, 0.f, 0.f, 0.f};
            accu[m][n] = (f32x4){0.f, 0.f, 0.f, 0.f};
        }

    int arow_ = tid >> 3, alane = tid & 7;          // A: 32 rows/pass, 8x16B per row
    int brow_ = tid >> 4, blane = tid & 15;         // B: 16 rows/pass, 16xfloat4 per row
    int atok[4];
#pragma unroll
    for (int p = 0; p < 4; ++p) atok[p] = tokl[rowbase + p * 32 + arow_];

    for (int kt = 0; kt < HDIM / 64; ++kt) {
#pragma unroll
        for (int p = 0; p < 4; ++p) {               // stage A (bf16 gather)
            int r = p * 32 + arow_;
            uint4 v = make_uint4(0, 0, 0, 0);
            int tok = atok[p];
            if (tok >= 0)
                v = *(const uint4*)(xb + (size_t)tok * HDIM + kt * 64 + alane * 8);
            int sw = alane ^ (r & 7);
            *(uint4*)(aL + r * 64 + sw * 8) = v;
        }
#pragma unroll
        for (int p = 0; p < 8; ++p) {               // stage B gate+up (fp32->bf16)
            int r = p * 16 + brow_;
            const float* sg = wgp + (size_t)r * HDIM + kt * 64 + blane * 4;
            const float* su = wup + (size_t)r * HDIM + kt * 64 + blane * 4;
            float4 vg = *(const float4*)sg;
            float4 vu = *(const float4*)su;
            int sw = (blane >> 1) ^ (r & 7);
            int half = blane & 1;
            Pack4 pg, pu;
            pg.b[0] = (bf16_t)vg.x; pg.b[1] = (bf16_t)vg.y;
            pg.b[2] = (bf16_t)vg.z; pg.b[3] = (bf16_t)vg.w;
            pu.b[0] = (bf16_t)vu.x; pu.b[1] = (bf16_t)vu.y;
            pu.b[2] = (bf16_t)vu.z; pu.b[3] = (bf16_t)vu.w;
            *(unsigned long long*)(gL + r * 64 + sw * 8 + half * 4) = pg.u64;
            *(unsigned long long*)(uL + r * 64 + sw * 8 + half * 4) = pu.u64;
        }
        __syncthreads();
#pragma unroll
        for (int ks = 0; ks < 2; ++ks) {
            bf16x8 af[4], bg[4], bu[4];
            int slot = ks * 4 + (lane >> 4);
#pragma unroll
            for (int m = 0; m < 4; ++m)
                af[m] = frag_read(aL, wm * 64 + m * 16 + (lane & 15), slot);
#pragma unroll
            for (int n = 0; n < 4; ++n) {
                bg[n] = frag_read(gL, wn * 64 + n * 16 + (lane & 15), slot);
                bu[n] = frag_read(uL, wn * 64 + n * 16 + (lane & 15), slot);
            }
#pragma unroll
            for (int m = 0; m < 4; ++m)
#pragma unroll
                for (int n = 0; n < 4; ++n) {
                    accg[m][n] = mfma16(af[m], bg[n], accg[m][n]);
                    accu[m][n] = mfma16(af[m], bu[n], accu[m][n]);
                }
        }
        __syncthreads();
    }
    int col0 = nt * 128 + wn * 64 + (lane & 15);
#pragma unroll
    for (int m = 0; m < 4; ++m) {
        int rloc = wm * 64 + m * 16 + ((lane >> 4) << 2);
#pragma unroll
        for (int ri = 0; ri < 4; ++ri) {
            bf16_t* dst = hbuf + (size_t)(rowbase + rloc + ri) * IDIM + col0;
#pragma unroll
            for (int n = 0; n < 4; ++n) {
                float g = accg[m][n][ri], u = accu[m][n][ri];
                float h = g / (1.f + __expf(-g)) * u;
                dst[n * 16] = (bf16_t)h;
            }
        }
    }
}

// ---------------- shared MLP part 1 ----------------
__global__ __launch_bounds__(256, 2) void k_mlp1_shared(
        const bf16_t* __restrict__ xb, const float* __restrict__ swg,
        const float* __restrict__ swu, bf16_t* __restrict__ shbuf) {
    int bid = blockIdx.x;
    int mt = bid / 22, nt = bid % 22;
    int rowbase = mt * 128;
    const float* wgp = swg + (size_t)(nt * 128) * HDIM;
    const float* wup = swu + (size_t)(nt * 128) * HDIM;

    __shared__ bf16_t aL[128 * 64];
    __shared__ bf16_t gL[128 * 64];
    __shared__ bf16_t uL[128 * 64];

    int tid = threadIdx.x;
    int lane = tid & 63;
    int wid = tid >> 6;
    int wm = wid >> 1, wn = wid & 1;

    f32x4 accg[4][4], accu[4][4];
#pragma unroll
    for (int m = 0; m < 4; ++m)
#pragma unroll
        for (int n = 0; n < 4; ++n) {
            accg[m][n] = (f32x4){0.f, 0.f, 0.f, 0.f};
            accu[m][n] = (f32x4){0.f, 0.f, 0.f, 0.f};
        }
    int arow_ = tid >> 3, alane = tid & 7;
    int brow_ = tid >> 4, blane = tid & 15;

    for (int kt = 0; kt < HDIM / 64; ++kt) {
#pragma unroll
        for (int p = 0; p < 4; ++p) {
            int r = p * 32 + arow_;
            uint4 v = *(const uint4*)(xb + (size_t)(rowbase + r) * HDIM + kt * 64 + alane * 8);
            int sw = alane ^ (r & 7);
            *(uint4*)(aL + r * 64 + sw * 8) = v;
        }
#pragma unroll
        for (int p = 0; p < 8; ++p) {
            int r = p * 16 + brow_;
            float4 vg = *(const float4*)(wgp + (size_t)r * HDIM + kt * 64 + blane * 4);
            float4 vu = *(const float4*)(wup + (size_t)r * HDIM + kt * 64 + blane * 4);
            int sw = (blane >> 1) ^ (r & 7);
            int half = blane & 1;
            Pack4 pg, pu;
            pg.b[0] = (bf16_t)vg.x; pg.b[1] = (bf16_t)vg.y;
            pg.b[2] = (bf16_t)vg.z; pg.b[3] = (bf16_t)vg.w;
            pu.b[0] = (bf16_t)vu.x; pu.b[1] = (bf16_t)vu.y;
            pu.b[2] = (bf16_t)vu.z; pu.b[3] = (bf16_t)vu.w;
            *(unsigned long long*)(gL + r * 64 + sw * 8 + half * 4) = pg.u64;
            *(unsigned long long*)(uL + r * 64 + sw * 8 + half * 4) = pu.u64;
        }
        __syncthreads();
#pragma unroll
        for (int ks = 0; ks < 2; ++ks) {
            bf16x8 af[4], bg[4], bu[4];
            int slot = ks * 4 + (lane >> 4);
#pragma unroll
            for (int m = 0; m < 4; ++m)
                af[m] = frag_read(aL, wm * 64 + m * 16 + (lane & 15), slot);
#pragma unroll
            for (int n = 0; n < 4; ++n) {
                bg[n] = frag_read(gL, wn * 64 + n * 16 + (lane & 15), slot);
                bu[n] = frag_read(uL, wn * 64 + n * 16 + (lane & 15), slot);
            }
#pragma unroll
            for (int m = 0; m < 4; ++m)
#pragma unroll
                for (int n = 0; n < 4; ++n) {
                    accg[m][n] = mfma16(af[m], bg[n], accg[m][n]);
                    accu[m][n] = mfma16(af[m], bu[n], accu[m][n]);
                }
        }
        __syncthreads();
    }
    int col0 = nt * 128 + wn * 64 + (lane & 15);
#pragma unroll
    for (int m = 0; m < 4; ++m) {
        int rloc = wm * 64 + m * 16 + ((lane >> 4) << 2);
#pragma unroll
        for (int ri = 0; ri < 4; ++ri) {
            bf16_t* dst = shbuf + (size_t)(rowbase + rloc + ri) * SIDIM + col0;
#pragma unroll
            for (int n = 0; n < 4; ++n) {
                float g = accg[m][n][ri], u = accu[m][n][ri];
                float h = g / (1.f + __expf(-g)) * u;
                dst[n * 16] = (bf16_t)h;
            }
        }
    }
}

// ---------------- shared down-proj: out = SH @ swd^T (plain store) ----------------
__global__ __launch_bounds__(256, 2) void k_down_shared(
        const bf16_t* __restrict__ shbuf, const float* __restrict__ swd,
        float* __restrict__ out) {
    int bid = blockIdx.x;
    int mt = bid >> 4, nt = bid & 15;
    int rowbase = mt * 128;
    const float* wp = swd + (size_t)(nt * 128) * SIDIM;

    __shared__ bf16_t aL[128 * 64];
    __shared__ bf16_t bL[128 * 64];

    int tid = threadIdx.x;
    int lane = tid & 63;
    int wid = tid >> 6;
    int wm = wid >> 1, wn = wid & 1;

    f32x4 acc[4][4];
#pragma unroll
    for (int m = 0; m < 4; ++m)
#pragma unroll
        for (int n = 0; n < 4; ++n) acc[m][n] = (f32x4){0.f, 0.f, 0.f, 0.f};

    int arow_ = tid >> 3, alane = tid & 7;
    int brow_ = tid >> 4, blane = tid & 15;

    for (int kt = 0; kt < SIDIM / 64; ++kt) {
#pragma unroll
        for (int p = 0; p < 4; ++p) {
            int r = p * 32 + arow_;
            uint4 v = *(const uint4*)(shbuf + (size_t)(rowbase + r) * SIDIM + kt * 64 + alane * 8);
            int sw = alane ^ (r & 7);
            *(uint4*)(aL + r * 64 + sw * 8) = v;
        }
#pragma unroll
        for (int p = 0; p < 8; ++p) {
            int r = p * 16 + brow_;
            float4 v = *(const float4*)(wp + (size_t)r * SIDIM + kt * 64 + blane * 4);
            int sw = (blane >> 1) ^ (r & 7);
            int half = blane & 1;
            Pack4 pb;
            pb.b[0] = (bf16_t)v.x; pb.b[1] = (bf16_t)v.y;
            pb.b[2] = (bf16_t)v.z; pb.b[3] = (bf16_t)v.w;
            *(unsigned long long*)(bL + r * 64 + sw * 8 + half * 4) = pb.u64;
        }
        __syncthreads();
#pragma unroll
        for (int ks = 0; ks < 2; ++ks) {
            bf16x8 af[4], bf[4];
            int slot = ks * 4 + (lane >> 4);
#pragma unroll
            for (int m = 0; m < 4; ++m)
                af[m] = frag_read(aL, wm * 64 + m * 16 + (lane & 15), slot);
#pragma unroll
            for (int n = 0; n < 4; ++n)
                bf[n] = frag_read(bL, wn * 64 + n * 16 + (lane & 15), slot);
#pragma unroll
            for (int m = 0; m < 4; ++m)
#pragma unroll
                for (int n = 0; n < 4; ++n)
                    acc[m][n] = mfma16(af[m], bf[n], acc[m][n]);
        }
        __syncthreads();
    }
    int col0 = nt * 128 + wn * 64 + (lane & 15);
#pragma unroll
    for (int m = 0; m < 4; ++m) {
        int rloc = wm * 64 + m * 16 + ((lane >> 4) << 2);
#pragma unroll
        for (int ri = 0; ri < 4; ++ri) {
            float* dst = out + (size_t)(rowbase + rloc + ri) * HDIM + col0;
#pragma unroll
            for (int n = 0; n < 4; ++n) dst[n * 16] = acc[m][n][ri];
        }
    }
}

// ---------------- routed down-proj: out[tok] += w * (h @ wd^T) ----------------
__global__ __launch_bounds__(256, 2) void k_down_routed(
        const bf16_t* __restrict__ hbuf, const float* __restrict__ wd,
        const int* __restrict__ counts, const int* __restrict__ poff,
        const int* __restrict__ tokl, const float* __restrict__ wgtl,
        float* __restrict__ out) {
    int bid = blockIdx.x;
    int e = bid >> 7, rem = bid & 127;
    int mt = rem >> 4, nt = rem & 15;
    int cnt = counts[e];
    if (mt * 128 >= cnt) return;
    int rowbase = poff[e] + mt * 128;
    const float* wp = wd + (size_t)e * HDIM * IDIM + (size_t)(nt * 128) * IDIM;

    __shared__ bf16_t aL[128 * 64];
    __shared__ bf16_t bL[128 * 64];

    int tid = threadIdx.x;
    int lane = tid & 63;
    int wid = tid >> 6;
    int wm = wid >> 1, wn = wid & 1;

    f32x4 acc[4][4];
#pragma unroll
    for (int m = 0; m < 4; ++m)
#pragma unroll
        for (int n = 0; n < 4; ++n) acc[m][n] = (f32x4){0.f, 0.f, 0.f, 0.f};

    int arow_ = tid >> 3, alane = tid & 7;
    int brow_ = tid >> 4, blane = tid & 15;

    for (int kt = 0; kt < IDIM / 64; ++kt) {
#pragma unroll
        for (int p = 0; p < 4; ++p) {
            int r = p * 32 + arow_;
            uint4 v = *(const uint4*)(hbuf + (size_t)(rowbase + r) * IDIM + kt * 64 + alane * 8);
            int sw = alane ^ (r & 7);
            *(uint4*)(aL + r * 64 + sw * 8) = v;
        }
#pragma unroll
        for (int p = 0; p < 8; ++p) {
            int r = p * 16 + brow_;
            float4 v = *(const float4*)(wp + (size_t)r * IDIM + kt * 64 + blane * 4);
            int sw = (blane >> 1) ^ (r & 7);
            int half = blane & 1;
            Pack4 pb;
            pb.b[0] = (bf16_t)v.x; pb.b[1] = (bf16_t)v.y;
            pb.b[2] = (bf16_t)v.z; pb.b[3] = (bf16_t)v.w;
            *(unsigned long long*)(bL + r * 64 + sw * 8 + half * 4) = pb.u64;
        }
        __syncthreads();
#pragma unroll
        for (int ks = 0; ks < 2; ++ks) {
            bf16x8 af[4], bf[4];
            int slot = ks * 4 + (lane >> 4);
#pragma unroll
            for (int m = 0; m < 4; ++m)
                af[m] = frag_read(aL, wm * 64 + m * 16 + (lane & 15), slot);
#pragma unroll
            for (int n = 0; n < 4; ++n)
                bf[n] = frag_read(bL, wn * 64 + n * 16 + (lane & 15), slot);
#pragma unroll
            for (int m = 0; m < 4; ++m)
#pragma unroll
                for (int n = 0; n < 4; ++n)
                    acc[m][n] = mfma16(af[m], bf[n], acc[m][n]);
        }
        __syncthreads();
    }
    int col0 = nt * 128 + wn * 64 + (lane & 15);
#pragma unroll
    for (int m = 0; m < 4; ++m) {
        int rloc = wm * 64 + m * 16 + ((lane >> 4) << 2);
#pragma unroll
        for (int ri = 0; ri < 4; ++ri) {
            int row = rowbase + rloc + ri;
            int tok = tokl[row];
            if (tok < 0) continue;
            float wgt = wgtl[row];
            float* dst = out + (size_t)tok * HDIM + col0;
#pragma unroll
            for (int n = 0; n < 4; ++n)
                atomicAdd(dst + n * 16, wgt * acc[m][n][ri]);
        }
    }
}

extern "C" void kernel_launch(void* const* d_in, const int* in_sizes, int n_in,
                              void* d_out, int out_size, void* d_ws, size_t ws_size,
                              hipStream_t stream) {
    const float* x       = (const float*)d_in[0];
    const float* gate_w  = (const float*)d_in[1];
    const float* gate_b  = (const float*)d_in[2];
    const float* w_gate  = (const float*)d_in[3];
    const float* w_up    = (const float*)d_in[4];
    const float* w_down  = (const float*)d_in[5];
    const float* sw_gate = (const float*)d_in[6];
    const float* sw_up   = (const float*)d_in[7];
    const float* sw_down = (const float*)d_in[8];
    float* out = (float*)d_out;

    char* ws = (char*)d_ws;
    bf16_t* xb    = (bf16_t*)(ws + OFF_XBF);
    bf16_t* hbuf  = (bf16_t*)(ws + OFF_HBUF);
    bf16_t* shbuf = (bf16_t*)(ws + OFF_SHBUF);
    int*    topki = (int*)(ws + OFF_TOPKI);
    float*  topkw = (float*)(ws + OFF_TOPKW);
    int*    tokl  = (int*)(ws + OFF_TOKL);
    float*  wgtl  = (float*)(ws + OFF_WGTL);
    int*    counts= (int*)(ws + OFF_CNT);
    int*    poff  = (int*)(ws + OFF_POFF);

    hipMemsetAsync(counts, 0, 64, stream);
    k_convert<<<2048, 256, 0, stream>>>(x, xb, TTOK * HDIM);
    k_gate<<<TTOK, 256, 0, stream>>>(x, gate_w, gate_b, topki, topkw, counts);
    k_scan<<<1, 64, 0, stream>>>(counts, poff);
    k_compact<<<NEXP, 64, 0, stream>>>(topki, topkw, counts, poff, tokl, wgtl);
    k_mlp1_routed<<<NEXP * 8 * 11, 256, 0, stream>>>(xb, w_gate, w_up, counts, poff, tokl, hbuf);
    k_mlp1_shared<<<8 * 22, 256, 0, stream>>>(xb, sw_gate, sw_up, shbuf);
    k_down_shared<<<8 * 16, 256, 0, stream>>>(shbuf, sw_down, out);
    k_down_routed<<<NEXP * 8 * 16, 256, 0, stream>>>(hbuf, w_down, counts, poff, tokl, wgtl, out);
}